// Round 6
// baseline (230.895 us; speedup 1.0000x reference)
//
#include <hip/hip_runtime.h>
#include <hip/hip_bf16.h>
#include <stdint.h>

// Problem constants (static graph layout)
#define NB 64
#define NN 4096
#define NS 512
#define NC 128
#define NTOTAL (NB*NN)          // 262144
#define NE 4194304
#define KSENT 3
#define KOTHER 1792
#define KPG (KSENT+KOTHER)      // 1795
#define NP (NB*KPG)             // 114880
#define NSENT_TOT (NB*KSENT)    // 192
#define NOTHER (NN-NS)          // 3584

// d_out element offsets (f32 elements), concatenated flat in return order:
// x_out[114880,128], edge_index_new[2,E], batch_out[P], perm[P], score[P], num_edges[1]
#define OFF_X     0ull
#define OFF_EDGE  14704640ull
#define OFF_BATCH 23093248ull
#define OFF_PERM  23208128ull
#define OFF_SCORE 23323008ull
#define OFF_NE    23437888ull

#define NEBLK 512               // edge blocks
#define EPB   (NE/NEBLK)        // 8192 edges per block
#define STASH 2560              // kept/block: mean 1575, sd 36 -> +27 sigma
#define NGB   1024              // gather blocks
#define NBW   (NTOTAL/32)       // 8192 bitmap words

#define FLG_AGG (1ull<<62)
#define FLG_INC (2ull<<62)

// Module-scope scratch. ~2.5 MB.
__device__ float g_scores[NTOTAL];
__device__ int   g_perm[NP];
__device__ int   g_nodemap[NTOTAL];
__device__ uint32_t g_bits[NBW];               // kept-node bitmap
__device__ unsigned long long g_state[NEBLK];  // lookback: flag(2b)|value(32b)
__device__ int   g_done[NB];                   // per-graph producer counters

// f32 -> bf16 RNE, kept as f32. Ref is bf16-rounded.
__device__ __forceinline__ float bfr(float f){
  uint32_t u = __float_as_uint(f);
  uint32_t r = u + 0x7FFFu + ((u >> 16) & 1u);
  return __uint_as_float(r & 0xFFFF0000u);
}

// Bit-exact XLA:CPU EmitTanh (f32). Passing R2-R5.
__device__ __forceinline__ float xla_tanhf(float x){
#pragma clang fp contract(off)
  float xc = fminf(fmaxf(x, -7.90531110763549805f), 7.90531110763549805f);
  float x2 = __fmul_rn(xc, xc);
  float p = -2.76076847742355e-16f;
  p = __fadd_rn(__fmul_rn(p, x2),  2.00018790482477e-13f);
  p = __fadd_rn(__fmul_rn(p, x2), -8.60467152213735e-11f);
  p = __fadd_rn(__fmul_rn(p, x2),  5.12229709037114e-08f);
  p = __fadd_rn(__fmul_rn(p, x2),  1.48572235717979e-05f);
  p = __fadd_rn(__fmul_rn(p, x2),  6.37261928875436e-04f);
  p = __fadd_rn(__fmul_rn(p, x2),  4.89352455891786e-03f);
  p = __fmul_rn(xc, p);
  float q = 1.19825839466702e-06f;
  q = __fadd_rn(__fmul_rn(q, x2), 1.18534705686654e-04f);
  q = __fadd_rn(__fmul_rn(q, x2), 2.26843463243900e-03f);
  q = __fadd_rn(__fmul_rn(q, x2), 4.89352518554385e-03f);
  float r = __fdiv_rn(p, q);
  return (fabsf(x) < 0.0004f) ? x : r;
}

__device__ __forceinline__ unsigned long long skey(float s, int idx){
  uint32_t u = __float_as_uint(s);
  u = (u & 0x80000000u) ? ~u : (u | 0x80000000u);
  u = ~u;
  return ((unsigned long long)u << 32) | (uint32_t)idx;
}

// K1: blocks 0..63 = per-graph topk (spin on producer counters);
//     blocks 64..575 = scores producers (512 rows each, 8 per graph).
// Scores arithmetic bit-identical to R3-R5 (passed).
__global__ __launch_bounds__(512, 4) void k1(const float* __restrict__ x,
                                             const float* __restrict__ w){
  // topk workspace (used by spinner blocks only; all blocks allocate)
  __shared__ uint32_t keyA[NOTHER], keyB[NOTHER];
  __shared__ uint16_t idxA[NOTHER], idxB[NOTHER], rnk[NOTHER];
  __shared__ uint16_t cnt[8][256];
  __shared__ uint16_t tot[256], dbase[256];
  __shared__ unsigned long long smin[8];
  __shared__ unsigned long long swin;
  __shared__ uint32_t bl[NN/32];

  int b = blockIdx.x, tid = threadIdx.x;
  int lane = tid & 63, wv = tid >> 6;

  if (b >= NB){
    // ---------------- producer ----------------
#pragma clang fp contract(off)
    int pb = b - NB;                    // 0..511
    g_state[pb] = 0ull;                 // re-arm K2 lookback (kernel-boundary vis)
    int row0 = pb * 512;
    g_nodemap[row0 + tid] = -1;         // fused nodemap init (own rows)

    int grp = tid >> 4, j = tid & 15;
    float wvv[8];
#pragma unroll
    for (int k = 0; k < 8; ++k) wvv[k] = w[k*16 + j];

    // ||w|| partial chain + guarded 16-lane tree (bit-identical to R5)
    float an = 0.f;
#pragma unroll
    for (int k = 0; k < 8; ++k) an = __fadd_rn(an, __fmul_rn(wvv[k], wvv[k]));
    float o;
    o = __shfl_down(an, 8); if (j < 8) an = __fadd_rn(an, o);
    o = __shfl_down(an, 4); if (j < 4) an = __fadd_rn(an, o);
    o = __shfl_down(an, 2); if (j < 2) an = __fadd_rn(an, o);
    o = __shfl_down(an, 1);
    float nrm = __fsqrt_rn(__fadd_rn(an, o));   // valid at j==0 only

    for (int it = 0; it < 16; ++it){
      int row = row0 + it*32 + grp;
      const float* rx = x + (size_t)row*NC;
      float ad = 0.f;
#pragma unroll
      for (int k = 0; k < 8; ++k)
        ad = __fadd_rn(ad, __fmul_rn(rx[k*16 + j], wvv[k]));
      o = __shfl_down(ad, 8); if (j < 8) ad = __fadd_rn(ad, o);
      o = __shfl_down(ad, 4); if (j < 4) ad = __fadd_rn(ad, o);
      o = __shfl_down(ad, 2); if (j < 2) ad = __fadd_rn(ad, o);
      o = __shfl_down(ad, 1);
      if (j == 0){
        float t = __fdiv_rn(__fadd_rn(ad, o), nrm);
        g_scores[row] = xla_tanhf(t);
      }
    }
    // device-scope release: data fences, then one counted add per block
    __threadfence();
    __syncthreads();
    if (tid == 0)
      __hip_atomic_fetch_add(&g_done[pb >> 3], 1, __ATOMIC_RELEASE,
                             __HIP_MEMORY_SCOPE_AGENT);
    return;
  }

  // ---------------- spinner: topk for graph b ----------------
  int g = b;
  if (tid == 0){
    while (__hip_atomic_load(&g_done[g], __ATOMIC_ACQUIRE,
                             __HIP_MEMORY_SCOPE_AGENT) < 8)
      __builtin_amdgcn_s_sleep(4);
    __hip_atomic_store(&g_done[g], 0, __ATOMIC_RELAXED,
                       __HIP_MEMORY_SCOPE_AGENT);   // re-arm for next call
  }
  __syncthreads();
  __threadfence();   // acquire for all threads

  const float* sg = g_scores + g*NN;

  if (tid < NN/32) bl[tid] = 0u;
  __syncthreads();

  // sentence top-3 (3 block-min extractions; (score desc, idx asc) key)
  unsigned long long key = skey(sg[tid], tid);
  for (int t = 0; t < KSENT; ++t){
    unsigned long long v = key;
#pragma unroll
    for (int off = 32; off; off >>= 1){
      unsigned long long o2 = __shfl_down(v, off);
      v = (o2 < v) ? o2 : v;
    }
    if (lane == 0) smin[wv] = v;
    __syncthreads();
    if (tid == 0){
      unsigned long long mm = smin[0];
      for (int w2 = 1; w2 < 8; ++w2) if (smin[w2] < mm) mm = smin[w2];
      swin = mm;
    }
    __syncthreads();
    unsigned long long winner = swin;
    if (key == winner){
      int idx = (int)(winner & 0xFFFFFFFFull);
      int node = g*NN + idx, p = g*KSENT + t;
      g_perm[p] = node;
      g_nodemap[node] = p;
      atomicOr(&bl[idx >> 5], 1u << (idx & 31));
      key = ~0ull;
    }
    __syncthreads();
  }

  // other top-1792 via stable LSD radix (4x8-bit), R3-R5 (passed)
  for (int i = tid; i < NOTHER; i += 512){
    uint32_t u = __float_as_uint(sg[NS + i]);
    u = (u & 0x80000000u) ? ~u : (u | 0x80000000u);
    keyA[i] = ~u;
    idxA[i] = (uint16_t)i;
  }
  __syncthreads();

  uint32_t* ksrc = keyA; uint32_t* kdst = keyB;
  uint16_t* isrc = idxA; uint16_t* idst = idxB;
  unsigned long long ltmask = (1ull << lane) - 1ull;
  int base = wv * 448;

  for (int pass = 0; pass < 4; ++pass){
    int shift = pass * 8;
    uint32_t* c32 = (uint32_t*)cnt[wv];
    c32[lane] = 0; c32[64 + lane] = 0;
    for (int r = 0; r < 7; ++r){
      int i = base + r*64 + lane;
      uint32_t k = ksrc[i];
      uint32_t d = (k >> shift) & 255u;
      unsigned long long m = ~0ull;
#pragma unroll
      for (int bb = 0; bb < 8; ++bb){
        unsigned long long bm2 = __ballot((d >> bb) & 1u);
        m &= ((d >> bb) & 1u) ? bm2 : ~bm2;
      }
      int rir = __popcll(m & ltmask);
      uint16_t bse = cnt[wv][d];
      rnk[i] = (uint16_t)(bse + rir);
      if ((m >> lane) == 1ull)
        cnt[wv][d] = (uint16_t)(bse + __popcll(m));
    }
    __syncthreads();
    if (tid < 256){
      int s = 0;
#pragma unroll
      for (int w2 = 0; w2 < 8; ++w2){
        int t2 = cnt[w2][tid]; cnt[w2][tid] = (uint16_t)s; s += t2;
      }
      tot[tid] = (uint16_t)s;
    }
    __syncthreads();
    if (tid < 64){
      int b4 = tid*4;
      int s0=tot[b4], s1=tot[b4+1], s2=tot[b4+2], s3=tot[b4+3];
      int lsum = s0+s1+s2+s3;
      int sc = lsum;
      for (int off = 1; off < 64; off <<= 1){
        int vv = __shfl_up(sc, off);
        if (lane >= off) sc += vv;
      }
      int excl = sc - lsum;
      dbase[b4]   = (uint16_t)excl;
      dbase[b4+1] = (uint16_t)(excl + s0);
      dbase[b4+2] = (uint16_t)(excl + s0 + s1);
      dbase[b4+3] = (uint16_t)(excl + s0 + s1 + s2);
    }
    __syncthreads();
    {
      int idx = tid;
#pragma unroll
      for (int kk = 0; kk < 4; ++kk){
        int w2 = (idx >> 8) & 7, d2 = idx & 255;
        cnt[w2][d2] = (uint16_t)(cnt[w2][d2] + dbase[d2]);
        idx += 512;
      }
    }
    __syncthreads();
    for (int r = 0; r < 7; ++r){
      int i = base + r*64 + lane;
      uint32_t k = ksrc[i];
      uint32_t d = (k >> shift) & 255u;
      int dest = cnt[wv][d] + rnk[i];
      kdst[dest] = k; idst[dest] = isrc[i];
    }
    __syncthreads();
    uint32_t* tk = ksrc; ksrc = kdst; kdst = tk;
    uint16_t* ti = isrc; isrc = idst; idst = ti;
  }
  for (int jj = tid; jj < KOTHER; jj += 512){
    int li = NS + (int)isrc[jj];
    int node = g*NN + li;
    int p = NSENT_TOT + g*KOTHER + jj;
    g_perm[p] = node;
    g_nodemap[node] = p;
    atomicOr(&bl[li >> 5], 1u << (li & 31));
  }
  __syncthreads();
  if (tid < NN/32) g_bits[g*(NN/32) + tid] = bl[tid];
}

// K2: blocks 0..511 = edges (bitmap keep-test, lookback compaction,
//     per-block tail drop-slice fill); blocks 512..1535 = gather.
__global__ __launch_bounds__(512, 6) void k2(const int* __restrict__ ei,
                                             const float* __restrict__ x,
                                             float* __restrict__ out){
  __shared__ uint32_t bm[NBW];    // 32 KB
  __shared__ int2 rc[STASH];      // 20 KB
  __shared__ int wsum[8];
  __shared__ int s_off;
  int b = blockIdx.x, tid = threadIdx.x;

  if (b >= NEBLK){
    // ---------------- gather + side outputs ----------------
    const size_t total4 = (size_t)NP*NC/4;
    for (size_t q = (size_t)(b - NEBLK)*512 + tid; q < total4;
         q += (size_t)NGB*512){
      int p  = (int)(q >> 5);
      int c4 = (int)(q & 31);
      int node = g_perm[p];
      float s = g_scores[node];
      float4 v = *(const float4*)(x + (size_t)node*NC + c4*4);
      float4 o;
      o.x = bfr(__fmul_rn(v.x, s));
      o.y = bfr(__fmul_rn(v.y, s));
      o.z = bfr(__fmul_rn(v.z, s));
      o.w = bfr(__fmul_rn(v.w, s));
      *(float4*)(out + OFF_X + (size_t)p*NC + c4*4) = o;
      if (c4 == 0){
        out[OFF_BATCH + p] = bfr((float)(node >> 12));
        out[OFF_PERM  + p] = bfr((float)node);
        out[OFF_SCORE + p] = bfr(s);
      }
    }
    return;
  }

  // ---------------- edges ----------------
  int lane = tid & 63, wid = tid >> 6;
  int base = b * EPB;
  unsigned long long ltm = (1ull << lane) - 1ull;

  { // stage bitmap: 8192 words / 512 thr = 4 x dwordx4
    uint4* d4 = (uint4*)bm;
    const uint4* s4 = (const uint4*)g_bits;
#pragma unroll
    for (int kk = 0; kk < 4; ++kk) d4[tid + kk*512] = s4[tid + kk*512];
  }
  if (tid == 0) s_off = 0;
  __syncthreads();

  // Phase A: keep flags from LDS bitmap, stable local positions, stash
  int running = 0;
  for (int s = 0; s < EPB; s += 512){
    int e = base + s + tid;
    int u = ei[e], v = ei[NE + e];
    bool keep = ((bm[u >> 5] >> (u & 31)) & 1u) &&
                ((bm[v >> 5] >> (v & 31)) & 1u);
    unsigned long long m = __ballot(keep);
    if (lane == 0) wsum[wid] = __popcll(m);
    __syncthreads();
    int wbase = 0;
#pragma unroll
    for (int w2 = 0; w2 < 8; ++w2) if (w2 < wid) wbase += wsum[w2];
    int tot = 0;
#pragma unroll
    for (int w2 = 0; w2 < 8; ++w2) tot += wsum[w2];
    if (keep){
      int lp = running + wbase + __popcll(m & ltm);
      if (lp < STASH){
        int2 p; p.x = g_nodemap[u]; p.y = g_nodemap[v]; rc[lp] = p;
      }
    }
    running += tot;
    __syncthreads();
  }
  int myc = running;

  // Phase B: decoupled lookback (wave 0) — R4/R5 (passed)
  if (b == 0){
    if (tid == 0)
      atomicExch(&g_state[0], FLG_INC | (unsigned long long)(uint32_t)myc);
  } else if (wid == 0){
    if (lane == 0)
      atomicExch(&g_state[b], FLG_AGG | (unsigned long long)(uint32_t)myc);
    int prev = 0, win = b - 1;
    bool done = false;
    while (!done){
      int idxl = win - lane;
      unsigned long long st = (idxl >= 0) ? atomicAdd(&g_state[idxl], 0ull)
                                          : FLG_INC;
      unsigned f = (unsigned)(st >> 62);
      unsigned long long readym = __ballot(f != 0u);
      unsigned long long incm   = __ballot(f == 2u);
      if (incm){
        int l0 = __ffsll((long long)incm) - 1;
        unsigned long long needm = (l0 == 63) ? ~0ull : ((1ull << (l0+1)) - 1ull);
        if ((readym & needm) == needm){
          int contrib = (lane <= l0) ? (int)(uint32_t)st : 0;
#pragma unroll
          for (int off = 32; off; off >>= 1)
            contrib += __shfl_down(contrib, off);
          if (lane == 0) prev += contrib;
          done = true;
        }
      } else if (readym == ~0ull){
        int contrib = (int)(uint32_t)st;
#pragma unroll
        for (int off = 32; off; off >>= 1)
          contrib += __shfl_down(contrib, off);
        if (lane == 0) prev += contrib;
        win -= 64;
      } else {
        __builtin_amdgcn_s_sleep(2);
      }
    }
    if (lane == 0){
      atomicExch(&g_state[b], FLG_INC | (unsigned long long)(uint32_t)(prev + myc));
      s_off = prev;
      if (b == NEBLK-1)
        out[OFF_NE] = bfr((float)(prev + myc));
    }
  }
  __syncthreads();
  int off = s_off;

  // Phase C: write kept edges from stash (coalesced)
  int lim = myc < STASH ? myc : STASH;
  for (int i = tid; i < lim; i += 512){
    int2 p = rc[i];
    out[OFF_EDGE + off + i]      = bfr((float)p.x);
    out[OFF_EDGE + NE + off + i] = bfr((float)p.y);
  }
  // Rare fallback: stash overflow -> recompute positions
  if (myc > STASH){
    running = 0;
    __syncthreads();
    for (int s = 0; s < EPB; s += 512){
      int e = base + s + tid;
      int u = ei[e], v = ei[NE + e];
      bool keep = ((bm[u >> 5] >> (u & 31)) & 1u) &&
                  ((bm[v >> 5] >> (v & 31)) & 1u);
      unsigned long long m = __ballot(keep);
      if (lane == 0) wsum[wid] = __popcll(m);
      __syncthreads();
      int wbase = 0;
#pragma unroll
      for (int w2 = 0; w2 < 8; ++w2) if (w2 < wid) wbase += wsum[w2];
      int tot = 0;
#pragma unroll
      for (int w2 = 0; w2 < 8; ++w2) tot += wsum[w2];
      if (keep){
        int lp = running + wbase + __popcll(m & ltm);
        if (lp >= STASH){
          out[OFF_EDGE + off + lp]      = bfr((float)g_nodemap[u]);
          out[OFF_EDGE + NE + off + lp] = bfr((float)g_nodemap[v]);
        }
      }
      running += tot;
      __syncthreads();
    }
  }

  // Tail drop-slice: block b fills [NE - dropoff - drops, NE - dropoff)
  // with -1 in both rows. Slices tile [T, NE) exactly; all values equal,
  // so no ordering/sync needed.
  int drops = EPB - myc;
  int dropoff = base - off;
  int t0 = NE - dropoff - drops;
  for (int i = tid; i < drops; i += 512){
    out[OFF_EDGE + t0 + i]      = -1.0f;
    out[OFF_EDGE + NE + t0 + i] = -1.0f;
  }
}

extern "C" void kernel_launch(void* const* d_in, const int* in_sizes, int n_in,
                              void* d_out, int out_size, void* d_ws, size_t ws_size,
                              hipStream_t stream) {
  const float* x = (const float*)d_in[0];
  const float* w = (const float*)d_in[1];
  const int*   ei = (const int*)d_in[2];
  float* out = (float*)d_out;

  hipLaunchKernelGGL(k1, dim3(NB + 512),     dim3(512), 0, stream, x, w);
  hipLaunchKernelGGL(k2, dim3(NEBLK + NGB),  dim3(512), 0, stream, ei, x, out);
}

// Round 7
// 90.895 us; speedup vs baseline: 2.5402x; 2.5402x over previous
//
#include <hip/hip_runtime.h>
#include <hip/hip_bf16.h>
#include <stdint.h>

// Problem constants (static graph layout)
#define NB 64
#define NN 4096
#define NS 512
#define NC 128
#define NTOTAL (NB*NN)          // 262144
#define NE 4194304
#define KSENT 3
#define KOTHER 1792
#define KPG (KSENT+KOTHER)      // 1795
#define NP (NB*KPG)             // 114880
#define NSENT_TOT (NB*KSENT)    // 192
#define NOTHER (NN-NS)          // 3584

// d_out element offsets (f32 elements), concatenated flat in return order:
// x_out[114880,128], edge_index_new[2,E], batch_out[P], perm[P], score[P], num_edges[1]
#define OFF_X     0ull
#define OFF_EDGE  14704640ull
#define OFF_BATCH 23093248ull
#define OFF_PERM  23208128ull
#define OFF_SCORE 23323008ull
#define OFF_NE    23437888ull

#define NEBLK 512               // edge blocks
#define EPB   (NE/NEBLK)        // 8192 edges per block
#define STASH 2560              // kept/block: mean 1575, sd 36 -> +27 sigma
#define NGB   1024              // gather blocks
#define NBW   (NTOTAL/32)       // 8192 bitmap words

#define FLG_AGG (1ull<<62)
#define FLG_INC (2ull<<62)

// Module-scope scratch. ~2.5 MB.
__device__ float g_scores[NTOTAL];
__device__ int   g_perm[NP];
__device__ int   g_nodemap[NTOTAL];
__device__ uint32_t g_bits[NBW];               // kept-node bitmap
__device__ unsigned long long g_state[NEBLK];  // lookback: flag(2b)|value(32b)

// f32 -> bf16 RNE, kept as f32. Ref is bf16-rounded.
__device__ __forceinline__ float bfr(float f){
  uint32_t u = __float_as_uint(f);
  uint32_t r = u + 0x7FFFu + ((u >> 16) & 1u);
  return __uint_as_float(r & 0xFFFF0000u);
}

// Bit-exact XLA:CPU EmitTanh (f32). Passing R2-R6.
__device__ __forceinline__ float xla_tanhf(float x){
#pragma clang fp contract(off)
  float xc = fminf(fmaxf(x, -7.90531110763549805f), 7.90531110763549805f);
  float x2 = __fmul_rn(xc, xc);
  float p = -2.76076847742355e-16f;
  p = __fadd_rn(__fmul_rn(p, x2),  2.00018790482477e-13f);
  p = __fadd_rn(__fmul_rn(p, x2), -8.60467152213735e-11f);
  p = __fadd_rn(__fmul_rn(p, x2),  5.12229709037114e-08f);
  p = __fadd_rn(__fmul_rn(p, x2),  1.48572235717979e-05f);
  p = __fadd_rn(__fmul_rn(p, x2),  6.37261928875436e-04f);
  p = __fadd_rn(__fmul_rn(p, x2),  4.89352455891786e-03f);
  p = __fmul_rn(xc, p);
  float q = 1.19825839466702e-06f;
  q = __fadd_rn(__fmul_rn(q, x2), 1.18534705686654e-04f);
  q = __fadd_rn(__fmul_rn(q, x2), 2.26843463243900e-03f);
  q = __fadd_rn(__fmul_rn(q, x2), 4.89352518554385e-03f);
  float r = __fdiv_rn(p, q);
  return (fabsf(x) < 0.0004f) ? x : r;
}

// Quarter-wave-per-row scores; lane j owns the XLA vector-lane-j chain
// (elements 16k+j, k ascending, unfused mul+add), shfl 8/4/2/1 tree.
// Bit-identical to R3-R5 (passed). Fuses nodemap + lookback-state init.
__global__ __launch_bounds__(256) void k_scores(const float* __restrict__ x,
                                                const float* __restrict__ w){
#pragma clang fp contract(off)
  int tid = threadIdx.x;
  int gid = blockIdx.x*256 + tid;
  if (gid < NTOTAL) g_nodemap[gid] = -1;              // fused nm_init
  if (blockIdx.x == 0){ g_state[tid] = 0ull; g_state[256+tid] = 0ull; }

  int grp = tid >> 4, j = tid & 15;
  int row = blockIdx.x*16 + grp;
  const float* rx = x + (size_t)row*NC;

  float wv[8];
#pragma unroll
  for (int k = 0; k < 8; ++k) wv[k] = w[k*16 + j];

  float an = 0.f, ad = 0.f;
#pragma unroll
  for (int k = 0; k < 8; ++k) an = __fadd_rn(an, __fmul_rn(wv[k], wv[k]));
#pragma unroll
  for (int k = 0; k < 8; ++k) ad = __fadd_rn(ad, __fmul_rn(rx[k*16 + j], wv[k]));

  float o;
  o = __shfl_down(an, 8); if (j < 8) an = __fadd_rn(an, o);
  o = __shfl_down(ad, 8); if (j < 8) ad = __fadd_rn(ad, o);
  o = __shfl_down(an, 4); if (j < 4) an = __fadd_rn(an, o);
  o = __shfl_down(ad, 4); if (j < 4) ad = __fadd_rn(ad, o);
  o = __shfl_down(an, 2); if (j < 2) an = __fadd_rn(an, o);
  o = __shfl_down(ad, 2); if (j < 2) ad = __fadd_rn(ad, o);
  o = __shfl_down(an, 1);
  float o2 = __shfl_down(ad, 1);
  if (j == 0){
    float nrm = __fsqrt_rn(__fadd_rn(an, o));
    float acc = __fadd_rn(ad, o2);
    float t = __fdiv_rn(acc, nrm);
    g_scores[row] = xla_tanhf(t);
  }
}

// Sentence key: ascending u64 == (score descending, index ascending).
__device__ __forceinline__ unsigned long long skey(float s, int idx){
  uint32_t u = __float_as_uint(s);
  u = (u & 0x80000000u) ? ~u : (u | 0x80000000u);
  u = ~u;
  return ((unsigned long long)u << 32) | (uint32_t)idx;
}

// One block per graph: sentence top-3 via 3 block-min extractions; other
// top-1792 via stable LSD radix (4x8-bit). Sets nodemap + kept-bitmap words
// for its own graph (128 words, built in LDS). (R5 verbatim, passed.)
__global__ __launch_bounds__(512) void k_topk(){
  __shared__ uint32_t keyA[NOTHER], keyB[NOTHER];
  __shared__ uint16_t idxA[NOTHER], idxB[NOTHER], rnk[NOTHER];
  __shared__ uint16_t cnt[8][256];
  __shared__ uint16_t tot[256], dbase[256];
  __shared__ unsigned long long smin[8];
  __shared__ unsigned long long swin;
  __shared__ uint32_t bl[NN/32];   // 128 words: this graph's kept bitmap

  int g = blockIdx.x, tid = threadIdx.x;
  int lane = tid & 63, wv = tid >> 6;
  const float* sg = g_scores + g*NN;

  if (tid < NN/32) bl[tid] = 0u;
  __syncthreads();

  unsigned long long key = skey(sg[tid], tid);
  for (int t = 0; t < KSENT; ++t){
    unsigned long long v = key;
#pragma unroll
    for (int off = 32; off; off >>= 1){
      unsigned long long o = __shfl_down(v, off);
      v = (o < v) ? o : v;
    }
    if (lane == 0) smin[wv] = v;
    __syncthreads();
    if (tid == 0){
      unsigned long long mm = smin[0];
      for (int w2 = 1; w2 < 8; ++w2) if (smin[w2] < mm) mm = smin[w2];
      swin = mm;
    }
    __syncthreads();
    unsigned long long winner = swin;
    if (key == winner){
      int idx = (int)(winner & 0xFFFFFFFFull);
      int node = g*NN + idx, p = g*KSENT + t;
      g_perm[p] = node;
      g_nodemap[node] = p;
      atomicOr(&bl[idx >> 5], 1u << (idx & 31));
      key = ~0ull;
    }
    __syncthreads();
  }

  for (int i = tid; i < NOTHER; i += 512){
    uint32_t u = __float_as_uint(sg[NS + i]);
    u = (u & 0x80000000u) ? ~u : (u | 0x80000000u);
    keyA[i] = ~u;
    idxA[i] = (uint16_t)i;
  }
  __syncthreads();

  uint32_t* ksrc = keyA; uint32_t* kdst = keyB;
  uint16_t* isrc = idxA; uint16_t* idst = idxB;
  unsigned long long ltmask = (1ull << lane) - 1ull;
  int base = wv * 448;

  for (int pass = 0; pass < 4; ++pass){
    int shift = pass * 8;
    uint32_t* c32 = (uint32_t*)cnt[wv];
    c32[lane] = 0; c32[64 + lane] = 0;
    for (int r = 0; r < 7; ++r){
      int i = base + r*64 + lane;
      uint32_t k = ksrc[i];
      uint32_t d = (k >> shift) & 255u;
      unsigned long long m = ~0ull;
#pragma unroll
      for (int b = 0; b < 8; ++b){
        unsigned long long bb = __ballot((d >> b) & 1u);
        m &= ((d >> b) & 1u) ? bb : ~bb;
      }
      int rir = __popcll(m & ltmask);
      uint16_t bse = cnt[wv][d];
      rnk[i] = (uint16_t)(bse + rir);
      if ((m >> lane) == 1ull)
        cnt[wv][d] = (uint16_t)(bse + __popcll(m));
    }
    __syncthreads();
    if (tid < 256){
      int s = 0;
#pragma unroll
      for (int w2 = 0; w2 < 8; ++w2){
        int t2 = cnt[w2][tid]; cnt[w2][tid] = (uint16_t)s; s += t2;
      }
      tot[tid] = (uint16_t)s;
    }
    __syncthreads();
    if (tid < 64){
      int b4 = tid*4;
      int s0=tot[b4], s1=tot[b4+1], s2=tot[b4+2], s3=tot[b4+3];
      int lsum = s0+s1+s2+s3;
      int sc = lsum;
      for (int off = 1; off < 64; off <<= 1){
        int vv = __shfl_up(sc, off);
        if (lane >= off) sc += vv;
      }
      int excl = sc - lsum;
      dbase[b4]   = (uint16_t)excl;
      dbase[b4+1] = (uint16_t)(excl + s0);
      dbase[b4+2] = (uint16_t)(excl + s0 + s1);
      dbase[b4+3] = (uint16_t)(excl + s0 + s1 + s2);
    }
    __syncthreads();
    {
      int idx = tid;
#pragma unroll
      for (int kk = 0; kk < 4; ++kk){
        int w2 = (idx >> 8) & 7, d2 = idx & 255;
        cnt[w2][d2] = (uint16_t)(cnt[w2][d2] + dbase[d2]);
        idx += 512;
      }
    }
    __syncthreads();
    for (int r = 0; r < 7; ++r){
      int i = base + r*64 + lane;
      uint32_t k = ksrc[i];
      uint32_t d = (k >> shift) & 255u;
      int dest = cnt[wv][d] + rnk[i];
      kdst[dest] = k; idst[dest] = isrc[i];
    }
    __syncthreads();
    uint32_t* tk = ksrc; ksrc = kdst; kdst = tk;
    uint16_t* ti = isrc; isrc = idst; idst = ti;
  }
  for (int j = tid; j < KOTHER; j += 512){
    int li = NS + (int)isrc[j];
    int node = g*NN + li;
    int p = NSENT_TOT + g*KOTHER + j;
    g_perm[p] = node;
    g_nodemap[node] = p;
    atomicOr(&bl[li >> 5], 1u << (li & 31));
  }
  __syncthreads();
  if (tid < NN/32) g_bits[g*(NN/32) + tid] = bl[tid];
}

// K2: blocks 0..511 = edges (bitmap keep-test, lookback compaction,
//     per-block tail drop-slice fill); blocks 512..1535 = gather.
// (R6 verbatim — this half of R6 was fast; k1 was the regression.)
__global__ __launch_bounds__(512) void k2(const int* __restrict__ ei,
                                          const float* __restrict__ x,
                                          float* __restrict__ out){
  __shared__ uint32_t bm[NBW];    // 32 KB
  __shared__ int2 rc[STASH];      // 20 KB
  __shared__ int wsum[8];
  __shared__ int s_off;
  int b = blockIdx.x, tid = threadIdx.x;

  if (b >= NEBLK){
    // ---------------- gather + side outputs ----------------
    const size_t total4 = (size_t)NP*NC/4;
    for (size_t q = (size_t)(b - NEBLK)*512 + tid; q < total4;
         q += (size_t)NGB*512){
      int p  = (int)(q >> 5);
      int c4 = (int)(q & 31);
      int node = g_perm[p];
      float s = g_scores[node];
      float4 v = *(const float4*)(x + (size_t)node*NC + c4*4);
      float4 o;
      o.x = bfr(__fmul_rn(v.x, s));
      o.y = bfr(__fmul_rn(v.y, s));
      o.z = bfr(__fmul_rn(v.z, s));
      o.w = bfr(__fmul_rn(v.w, s));
      *(float4*)(out + OFF_X + (size_t)p*NC + c4*4) = o;
      if (c4 == 0){
        out[OFF_BATCH + p] = bfr((float)(node >> 12));
        out[OFF_PERM  + p] = bfr((float)node);
        out[OFF_SCORE + p] = bfr(s);
      }
    }
    return;
  }

  // ---------------- edges ----------------
  int lane = tid & 63, wid = tid >> 6;
  int base = b * EPB;
  unsigned long long ltm = (1ull << lane) - 1ull;

  { // stage bitmap: 8192 words / 512 thr = 4 x dwordx4
    uint4* d4 = (uint4*)bm;
    const uint4* s4 = (const uint4*)g_bits;
#pragma unroll
    for (int kk = 0; kk < 4; ++kk) d4[tid + kk*512] = s4[tid + kk*512];
  }
  if (tid == 0) s_off = 0;
  __syncthreads();

  // Phase A: keep flags from LDS bitmap, stable local positions, stash
  int running = 0;
  for (int s = 0; s < EPB; s += 512){
    int e = base + s + tid;
    int u = ei[e], v = ei[NE + e];
    bool keep = ((bm[u >> 5] >> (u & 31)) & 1u) &&
                ((bm[v >> 5] >> (v & 31)) & 1u);
    unsigned long long m = __ballot(keep);
    if (lane == 0) wsum[wid] = __popcll(m);
    __syncthreads();
    int wbase = 0;
#pragma unroll
    for (int w2 = 0; w2 < 8; ++w2) if (w2 < wid) wbase += wsum[w2];
    int tot = 0;
#pragma unroll
    for (int w2 = 0; w2 < 8; ++w2) tot += wsum[w2];
    if (keep){
      int lp = running + wbase + __popcll(m & ltm);
      if (lp < STASH){
        int2 p; p.x = g_nodemap[u]; p.y = g_nodemap[v]; rc[lp] = p;
      }
    }
    running += tot;
    __syncthreads();
  }
  int myc = running;

  // Phase B: decoupled lookback (wave 0) — R4-R6 (passed)
  if (b == 0){
    if (tid == 0)
      atomicExch(&g_state[0], FLG_INC | (unsigned long long)(uint32_t)myc);
  } else if (wid == 0){
    if (lane == 0)
      atomicExch(&g_state[b], FLG_AGG | (unsigned long long)(uint32_t)myc);
    int prev = 0, win = b - 1;
    bool done = false;
    while (!done){
      int idxl = win - lane;
      unsigned long long st = (idxl >= 0) ? atomicAdd(&g_state[idxl], 0ull)
                                          : FLG_INC;
      unsigned f = (unsigned)(st >> 62);
      unsigned long long readym = __ballot(f != 0u);
      unsigned long long incm   = __ballot(f == 2u);
      if (incm){
        int l0 = __ffsll((long long)incm) - 1;
        unsigned long long needm = (l0 == 63) ? ~0ull : ((1ull << (l0+1)) - 1ull);
        if ((readym & needm) == needm){
          int contrib = (lane <= l0) ? (int)(uint32_t)st : 0;
#pragma unroll
          for (int off = 32; off; off >>= 1)
            contrib += __shfl_down(contrib, off);
          if (lane == 0) prev += contrib;
          done = true;
        }
      } else if (readym == ~0ull){
        int contrib = (int)(uint32_t)st;
#pragma unroll
        for (int off = 32; off; off >>= 1)
          contrib += __shfl_down(contrib, off);
        if (lane == 0) prev += contrib;
        win -= 64;
      } else {
        __builtin_amdgcn_s_sleep(2);
      }
    }
    if (lane == 0){
      atomicExch(&g_state[b], FLG_INC | (unsigned long long)(uint32_t)(prev + myc));
      s_off = prev;
      if (b == NEBLK-1)
        out[OFF_NE] = bfr((float)(prev + myc));
    }
  }
  __syncthreads();
  int off = s_off;

  // Phase C: write kept edges from stash (coalesced)
  int lim = myc < STASH ? myc : STASH;
  for (int i = tid; i < lim; i += 512){
    int2 p = rc[i];
    out[OFF_EDGE + off + i]      = bfr((float)p.x);
    out[OFF_EDGE + NE + off + i] = bfr((float)p.y);
  }
  // Rare fallback: stash overflow -> recompute positions
  if (myc > STASH){
    running = 0;
    __syncthreads();
    for (int s = 0; s < EPB; s += 512){
      int e = base + s + tid;
      int u = ei[e], v = ei[NE + e];
      bool keep = ((bm[u >> 5] >> (u & 31)) & 1u) &&
                  ((bm[v >> 5] >> (v & 31)) & 1u);
      unsigned long long m = __ballot(keep);
      if (lane == 0) wsum[wid] = __popcll(m);
      __syncthreads();
      int wbase = 0;
#pragma unroll
      for (int w2 = 0; w2 < 8; ++w2) if (w2 < wid) wbase += wsum[w2];
      int tot = 0;
#pragma unroll
      for (int w2 = 0; w2 < 8; ++w2) tot += wsum[w2];
      if (keep){
        int lp = running + wbase + __popcll(m & ltm);
        if (lp >= STASH){
          out[OFF_EDGE + off + lp]      = bfr((float)g_nodemap[u]);
          out[OFF_EDGE + NE + off + lp] = bfr((float)g_nodemap[v]);
        }
      }
      running += tot;
      __syncthreads();
    }
  }

  // Tail drop-slice: block b fills [NE - dropoff - drops, NE - dropoff)
  // with -1 in both rows. Slices tile [T, NE) exactly; values identical.
  int drops = EPB - myc;
  int dropoff = base - off;
  int t0 = NE - dropoff - drops;
  for (int i = tid; i < drops; i += 512){
    out[OFF_EDGE + t0 + i]      = -1.0f;
    out[OFF_EDGE + NE + t0 + i] = -1.0f;
  }
}

extern "C" void kernel_launch(void* const* d_in, const int* in_sizes, int n_in,
                              void* d_out, int out_size, void* d_ws, size_t ws_size,
                              hipStream_t stream) {
  const float* x = (const float*)d_in[0];
  const float* w = (const float*)d_in[1];
  const int*   ei = (const int*)d_in[2];
  float* out = (float*)d_out;

  hipLaunchKernelGGL(k_scores, dim3(NTOTAL/16),   dim3(256), 0, stream, x, w);
  hipLaunchKernelGGL(k_topk,   dim3(NB),          dim3(512), 0, stream);
  hipLaunchKernelGGL(k2,       dim3(NEBLK + NGB), dim3(512), 0, stream, ei, x, out);
}